// Round 19
// baseline (138.573 us; speedup 1.0000x reference)
//
#include <hip/hip_runtime.h>

#define N_NODES 50000
#define N_EDGES 800000
#define DIM 128
#define NBINS 782      // ceil(50000 / 64)
#define CAP 2048       // per-bin pair capacity
#define EPB 8192       // edges per binscat block
#define NSCAT 98       // ceil(800000 / 8192)

typedef _Float16 f16;
typedef _Float16 f16x4 __attribute__((ext_vector_type(4)));
typedef _Float16 f16x8 __attribute__((ext_vector_type(8)));
typedef float    f32x2 __attribute__((ext_vector_type(2)));
typedef float    f32x4 __attribute__((ext_vector_type(4)));
typedef unsigned short u16;
typedef unsigned char  u8;

__device__ inline int bucketof(int d) {
    if (d < 10) return 0;
    if (d < 13) return 1;
    if (d < 16) return 2;
    if (d < 19) return 3;
    if (d < 22) return 4;
    if (d < 26) return 5;
    if (d < 32) return 6;
    return 7;
}

// ---------------- zero binfill ----------------

__global__ __launch_bounds__(256) void k_zero(int* __restrict__ p) {
    int i = blockIdx.x * 256 + threadIdx.x;
    if (i < NBINS) p[i] = 0;
}

// ---- fused prep: x->fp8 (0..3124) + W frag-order (3125..3156) + binned scatter (3157..3254) ----

__global__ __launch_bounds__(256) void k_prepscat(const float* __restrict__ x, u8* __restrict__ x8,
                                                  const float* __restrict__ W1l, const float* __restrict__ W1r,
                                                  const float* __restrict__ W2l, const float* __restrict__ W2r,
                                                  f16* __restrict__ Wf1, f16* __restrict__ Wf2,
                                                  const int* __restrict__ src, const int* __restrict__ dst,
                                                  int* __restrict__ binfill, int* __restrict__ pairs) {
    int b = blockIdx.x;
    if (b < 3125) {
        int idx = b * 256 + threadIdx.x;             // 0..799,999 : 8 f32 -> 8 fp8 each
        const float* xp = x + (size_t)idx * 8;
        float4 v0 = *(const float4*)xp;
        float4 v1 = *(const float4*)(xp + 4);
        int r0 = 0, r1 = 0;
        r0 = __builtin_amdgcn_cvt_pk_fp8_f32(v0.x, v0.y, r0, false);
        r0 = __builtin_amdgcn_cvt_pk_fp8_f32(v0.z, v0.w, r0, true);
        r1 = __builtin_amdgcn_cvt_pk_fp8_f32(v1.x, v1.y, r1, false);
        r1 = __builtin_amdgcn_cvt_pk_fp8_f32(v1.z, v1.w, r1, true);
        uint2 w; w.x = (unsigned)r0; w.y = (unsigned)r1;
        *(uint2*)(x8 + (size_t)idx * 8) = w;
    } else if (b < 3157) {
        int t = (b - 3125) * 256 + threadIdx.x;      // 0..8191
        int layer = t >> 12;
        int nt = (t >> 9) & 7;
        int kk = (t >> 6) & 7;
        int lane = t & 63;
        int r = lane & 15, g = lane >> 4;
        int n = nt * 16 + r;
        const float* Wl_ = layer ? W2l : W1l;
        const float* Wr_ = layer ? W2r : W1r;
        f16x8 frag;
#pragma unroll
        for (int j = 0; j < 8; ++j) {
            int k = kk * 32 + g * 4 + (j & 3) + ((j >> 2) << 4);
            float f = (k < 128) ? Wl_[n * 128 + k] : Wr_[n * 128 + (k - 128)];
            frag[j] = (f16)f;
        }
        f16* dstp = (layer ? Wf2 : Wf1) + ((size_t)((nt * 8 + kk) * 64 + lane)) * 8;
        *(f16x8*)dstp = frag;
    } else {
        // binned scatter: 98 blocks, 8192 edges each; two-read LDS histogram (count, reserve, place)
        __shared__ int hist[NBINS];
        __shared__ int base[NBINS];
        int t = threadIdx.x;
        int e0 = (b - 3157) * EPB;
        for (int i = t; i < NBINS; i += 256) hist[i] = 0;
        __syncthreads();
#pragma unroll 4
        for (int j = 0; j < 32; ++j) {
            int e = e0 + j * 256 + t;
            if (e < N_EDGES) atomicAdd(&hist[dst[e] >> 6], 1);
        }
        __syncthreads();
        for (int i = t; i < NBINS; i += 256) base[i] = atomicAdd(&binfill[i], hist[i]);
        __syncthreads();
        for (int i = t; i < NBINS; i += 256) hist[i] = 0;
        __syncthreads();
#pragma unroll 4
        for (int j = 0; j < 32; ++j) {
            int e = e0 + j * 256 + t;
            if (e < N_EDGES) {
                int d = dst[e];
                int bin = d >> 6;
                int rk = atomicAdd(&hist[bin], 1);
                int pos = base[bin] + rk;
                if (pos < CAP) pairs[bin * CAP + pos] = (src[e] << 6) | (d & 63);
            }
        }
    }
}

// ---------------- bin solve: per-node degree/rowbeg/srt(u16)/bin-local degree-sorted order ----------------

__global__ __launch_bounds__(256) void k_binsolve(const int* __restrict__ pairs, const int* __restrict__ binfill,
                                                  u16* __restrict__ srt, int* __restrict__ rowbeg,
                                                  int* __restrict__ degA, int* __restrict__ order) {
    __shared__ int lcnt[64];
    __shared__ int lptr[64];
    __shared__ int lcur[64];
    __shared__ int h8[8];
    __shared__ int bb[8];
    int bin = blockIdx.x;
    int t = threadIdx.x;
    int p0 = bin * CAP;
    int cnt = min(binfill[bin], CAP);
    if (t < 64) lcnt[t] = 0;
    if (t < 8) h8[t] = 0;
    __syncthreads();
    for (int i = t; i < cnt; i += 256) atomicAdd(&lcnt[pairs[p0 + i] & 63], 1);
    __syncthreads();
    if (t < 64) {
        int d = lcnt[t];
        int v = d;
#pragma unroll
        for (int off = 1; off < 64; off <<= 1) {
            int u = __shfl_up(v, off);
            if (t >= off) v += u;
        }
        lptr[t] = v - d;
        lcur[t] = v - d;
    }
    __syncthreads();
    for (int i = t; i < cnt; i += 256) {
        int p = pairs[p0 + i];
        int slot = atomicAdd(&lcur[p & 63], 1);
        srt[p0 + slot] = (u16)(p >> 6);
    }
    int node = bin * 64 + t;
    bool act = (t < 64) && (node < N_NODES);
    int b = 0, r8 = 0;
    if (act) {
        rowbeg[node] = p0 + lptr[t];
        degA[node] = lcnt[t];
        b = bucketof(lcnt[t]);
        r8 = atomicAdd(&h8[b], 1);
    }
    __syncthreads();
    if (t == 0) {
        int r = 0;
#pragma unroll
        for (int i = 0; i < 8; ++i) { bb[i] = r; r += h8[i]; }
    }
    __syncthreads();
    if (act) order[bin * 64 + bb[b] + r8] = node;
}

// ---------------- FUSED layer (256 thr): fp8 gather (bin of 64 nodes -> LDS f16) + dual MFMA GEMM ----------------
// Gather: 16 groups x 16 lanes; lane = 8 fp8 = 8 B; row = 128 B = 2 cache lines. Plain srt loads (L2-retained).
// Self operand: layer 1 from f32 x (cast f16), layer 2 from f16 hh.

__global__ __launch_bounds__(256) void k_fused(const u8* __restrict__ X8, const float* __restrict__ Xf,
                                               const f16* __restrict__ Xh16, const u16* __restrict__ srt,
                                               const int* __restrict__ rowbeg, const int* __restrict__ degA,
                                               const int* __restrict__ order, const f16* __restrict__ Wf,
                                               const float* __restrict__ bias,
                                               float* __restrict__ C, f16* __restrict__ Cb16,
                                               u8* __restrict__ Cb8) {
    __shared__ f16 agg[64][136];
    int bin = blockIdx.x;
    int n0 = bin << 6;
    int t = threadIdx.x;
    int g = t >> 4, l16 = t & 15;
    int nvalid = N_NODES - n0; if (nvalid > 64) nvalid = 64;
    const u8* __restrict__ base = X8 + l16 * 8;

#pragma unroll
    for (int p = 0; p < 4; ++p) {
        int rank = p * 16 + g;
        if (rank < nvalid) {
            int node = order[n0 + rank];
            int m = node - n0;
            int beg = rowbeg[node];
            int d = degA[node];
            int end = beg + d;
            f32x2 A0[4], A1[4], A2[4], A3[4];
#pragma unroll
            for (int j = 0; j < 4; ++j) {
                A0[j] = (f32x2){0.f, 0.f}; A1[j] = (f32x2){0.f, 0.f};
                A2[j] = (f32x2){0.f, 0.f}; A3[j] = (f32x2){0.f, 0.f};
            }
            int e = beg;
#define GACC(Ar, w) { Ar[0] += __builtin_amdgcn_cvt_pk_f32_fp8((w).x, false); \
                      Ar[1] += __builtin_amdgcn_cvt_pk_f32_fp8((w).x, true);  \
                      Ar[2] += __builtin_amdgcn_cvt_pk_f32_fp8((w).y, false); \
                      Ar[3] += __builtin_amdgcn_cvt_pk_f32_fp8((w).y, true); }
            for (; e + 4 <= end; e += 4) {
                int s0 = srt[e];
                int s1 = srt[e + 1];
                int s2 = srt[e + 2];
                int s3 = srt[e + 3];
                uint2 w0 = *(const uint2*)(base + (size_t)s0 * DIM);
                uint2 w1 = *(const uint2*)(base + (size_t)s1 * DIM);
                uint2 w2 = *(const uint2*)(base + (size_t)s2 * DIM);
                uint2 w3 = *(const uint2*)(base + (size_t)s3 * DIM);
                GACC(A0, w0); GACC(A1, w1); GACC(A2, w2); GACC(A3, w3);
            }
            if (e < end)     { uint2 w = *(const uint2*)(base + (size_t)srt[e] * DIM); GACC(A0, w); }
            if (e + 1 < end) { uint2 w = *(const uint2*)(base + (size_t)srt[e + 1] * DIM); GACC(A1, w); }
            if (e + 2 < end) { uint2 w = *(const uint2*)(base + (size_t)srt[e + 2] * DIM); GACC(A2, w); }
#undef GACC
            float inv = 1.0f / fmaxf((float)d, 1.0f);
            f16x8 r;
#pragma unroll
            for (int j = 0; j < 4; ++j) {
                f32x2 s = (A0[j] + A1[j]) + (A2[j] + A3[j]);
                r[j * 2]     = (f16)(s.x * inv);
                r[j * 2 + 1] = (f16)(s.y * inv);
            }
            *(f16x8*)&agg[m][l16 * 8] = r;
        }
    }
    __syncthreads();

    int wave = t >> 6, lane = t & 63;
    int r = lane & 15, gg = lane >> 4;
    int rowloc = wave * 16 + r;
    size_t grow = (size_t)n0 + rowloc;
    size_t growc = (grow < N_NODES) ? grow : (N_NODES - 1);

    f32x4 acc[8];
#pragma unroll
    for (int nt = 0; nt < 8; ++nt) acc[nt] = (f32x4){0.f, 0.f, 0.f, 0.f};

#pragma unroll
    for (int kk = 0; kk < 8; ++kk) {
        f16x8 a;
        if (kk < 4) {
            f16x4 q0 = *(const f16x4*)&agg[rowloc][kk * 32 + gg * 4];
            f16x4 q1 = *(const f16x4*)&agg[rowloc][kk * 32 + gg * 4 + 16];
            a = __builtin_shufflevector(q0, q1, 0, 1, 2, 3, 4, 5, 6, 7);
        } else if (Xf) {
            const float* ar = Xf + growc * DIM + (kk - 4) * 32 + gg * 4;
            float4 u0 = *(const float4*)(ar);
            float4 u1 = *(const float4*)(ar + 16);
            a[0]=(f16)u0.x; a[1]=(f16)u0.y; a[2]=(f16)u0.z; a[3]=(f16)u0.w;
            a[4]=(f16)u1.x; a[5]=(f16)u1.y; a[6]=(f16)u1.z; a[7]=(f16)u1.w;
        } else {
            const f16* ar = Xh16 + growc * DIM + (kk - 4) * 32 + gg * 4;
            f16x4 q0 = *(const f16x4*)(ar);
            f16x4 q1 = *(const f16x4*)(ar + 16);
            a = __builtin_shufflevector(q0, q1, 0, 1, 2, 3, 4, 5, 6, 7);
        }
#pragma unroll
        for (int nt = 0; nt < 8; ++nt) {
            f16x8 b = *(const f16x8*)(Wf + ((size_t)((nt * 8 + kk) * 64 + lane)) * 8);
            acc[nt] = __builtin_amdgcn_mfma_f32_16x16x32_f16(a, b, acc[nt], 0, 0, 0);
        }
    }
    size_t rbase = (size_t)n0 + wave * 16 + gg * 4;
#pragma unroll
    for (int nt = 0; nt < 8; ++nt) {
        int colc = nt * 16 + r;
        float bv = bias[colc];
#pragma unroll
        for (int q = 0; q < 4; ++q) {
            size_t node = rbase + q;
            if (node < N_NODES) {
                float v = fmaxf(acc[nt][q] + bv, 0.f);
                if (C)    C[node * DIM + colc] = v;
                if (Cb16) Cb16[node * DIM + colc] = (f16)v;
                if (Cb8) {
                    int pk = __builtin_amdgcn_cvt_pk_fp8_f32(v, v, 0, false);
                    Cb8[node * DIM + colc] = (u8)(pk & 0xff);
                }
            }
        }
    }
}

// ---------------- launch ----------------

extern "C" void kernel_launch(void* const* d_in, const int* in_sizes, int n_in,
                              void* d_out, int out_size, void* d_ws, size_t ws_size,
                              hipStream_t stream) {
    const float* x   = (const float*)d_in[0];
    const int*   ei  = (const int*)d_in[1];
    const float* W1l = (const float*)d_in[2];
    const float* b1  = (const float*)d_in[3];
    const float* W1r = (const float*)d_in[4];
    const float* W2l = (const float*)d_in[5];
    const float* b2  = (const float*)d_in[6];
    const float* W2r = (const float*)d_in[7];
    float* out = (float*)d_out;

    const int* src = ei;
    const int* dst = ei + N_EDGES;

    char* ws = (char*)d_ws;
    int*  binfill = (int*)(ws + 0);              // 3,128 B (zeroed by k_zero)
    int*  degA    = (int*)(ws + 3200);           // 200,000 B
    int*  rowbeg  = (int*)(ws + 203264);         // 200,000 B
    int*  order   = (int*)(ws + 403264);         // 200,000 B
    u16*  srt     = (u16*)(ws + 603264);         // 3,203,072 B -> ends 3,806,336
    u8*   x8      = (u8*)(ws + 3806336);         // 6.4 MB fp8 x -> ends 10,206,336
    f16*  hh      = (f16*)(ws + 10206336);       // 12.8 MB f16 h -> ends 23,006,336
    int*  pairs   = (int*)(ws + 23006336);       // 6,406,144 B -> ends 29,412,480
    u8*   hh8     = (u8*)(ws + 23006336);        // 6.4 MB fp8 h (overlaps pairs; pairs dead after binsolve)
    f16*  Wf1     = (f16*)(ws + 29412480);       // 64 KB frag-order
    f16*  Wf2     = Wf1 + 32768;                 // 64 KB -> ends ~29.54 MB

    dim3 blk(256);
    k_zero<<<dim3(4), blk, 0, stream>>>(binfill);
    k_prepscat<<<dim3(3255), blk, 0, stream>>>(x, x8, W1l, W1r, W2l, W2r, Wf1, Wf2,
                                               src, dst, binfill, pairs);
    k_binsolve<<<dim3(NBINS), blk, 0, stream>>>(pairs, binfill, srt, rowbeg, degA, order);

    // layer 1: h = relu(agg8(x) @ W1l^T + b1 + x @ W1r^T)   -> hh (f16) + hh8 (fp8)
    k_fused<<<dim3(NBINS), blk, 0, stream>>>(x8, x, (const f16*)nullptr, srt, rowbeg, degA, order,
                                             Wf1, b1, (float*)nullptr, hh, hh8);

    // layer 2: out = relu(agg8(h) @ W2l^T + b2 + h @ W2r^T) -> out (f32)
    k_fused<<<dim3(NBINS), blk, 0, stream>>>(hh8, (const float*)nullptr, hh, srt, rowbeg, degA, order,
                                             Wf2, b2, out, (f16*)nullptr, (u8*)nullptr);
}

// Round 20
// 119.923 us; speedup vs baseline: 1.1555x; 1.1555x over previous
//
#include <hip/hip_runtime.h>

#define N_NODES 50000
#define N_EDGES 800000
#define DIM 128
#define NBINS 782      // ceil(50000 / 64)
#define CAP 2048       // per-bin pair capacity
#define EPB 8192       // edges per binscat block
#define NSCAT 98       // ceil(800000 / 8192)

typedef _Float16 f16;
typedef _Float16 f16x4 __attribute__((ext_vector_type(4)));
typedef _Float16 f16x8 __attribute__((ext_vector_type(8)));
typedef float    f32x2 __attribute__((ext_vector_type(2)));
typedef float    f32x4 __attribute__((ext_vector_type(4)));
typedef unsigned short u16;
typedef unsigned char  u8;

__device__ inline int bucketof(int d) {
    if (d < 10) return 0;
    if (d < 13) return 1;
    if (d < 16) return 2;
    if (d < 19) return 3;
    if (d < 22) return 4;
    if (d < 26) return 5;
    if (d < 32) return 6;
    return 7;
}

// ---------------- prep: x->fp8 (blocks 0..3124) + W frag-order (3125..3156) + zero binfill (3157) ----------------

__global__ __launch_bounds__(256) void k_prep(const float* __restrict__ x, u8* __restrict__ x8,
                                              const float* __restrict__ W1l, const float* __restrict__ W1r,
                                              const float* __restrict__ W2l, const float* __restrict__ W2r,
                                              f16* __restrict__ Wf1, f16* __restrict__ Wf2,
                                              int* __restrict__ binfill) {
    int b = blockIdx.x;
    if (b < 3125) {
        int idx = b * 256 + threadIdx.x;             // 0..799,999 : 8 f32 -> 8 fp8 each
        const float* xp = x + (size_t)idx * 8;
        float4 v0 = *(const float4*)xp;
        float4 v1 = *(const float4*)(xp + 4);
        int r0 = 0, r1 = 0;
        r0 = __builtin_amdgcn_cvt_pk_fp8_f32(v0.x, v0.y, r0, false);
        r0 = __builtin_amdgcn_cvt_pk_fp8_f32(v0.z, v0.w, r0, true);
        r1 = __builtin_amdgcn_cvt_pk_fp8_f32(v1.x, v1.y, r1, false);
        r1 = __builtin_amdgcn_cvt_pk_fp8_f32(v1.z, v1.w, r1, true);
        uint2 w; w.x = (unsigned)r0; w.y = (unsigned)r1;
        *(uint2*)(x8 + (size_t)idx * 8) = w;
    } else if (b < 3157) {
        int t = (b - 3125) * 256 + threadIdx.x;      // 0..8191
        int layer = t >> 12;
        int nt = (t >> 9) & 7;
        int kk = (t >> 6) & 7;
        int lane = t & 63;
        int r = lane & 15, g = lane >> 4;
        int n = nt * 16 + r;
        const float* Wl_ = layer ? W2l : W1l;
        const float* Wr_ = layer ? W2r : W1r;
        f16x8 frag;
#pragma unroll
        for (int j = 0; j < 8; ++j) {
            int k = kk * 32 + g * 4 + (j & 3) + ((j >> 2) << 4);
            float f = (k < 128) ? Wl_[n * 128 + k] : Wr_[n * 128 + (k - 128)];
            frag[j] = (f16)f;
        }
        f16* dstp = (layer ? Wf2 : Wf1) + ((size_t)((nt * 8 + kk) * 64 + lane)) * 8;
        *(f16x8*)dstp = frag;
    } else {
        for (int i = threadIdx.x; i < NBINS; i += 256) binfill[i] = 0;
    }
}

// ---------------- binned scatter ----------------

__global__ __launch_bounds__(1024) void k_binscat(const int* __restrict__ src, const int* __restrict__ dst,
                                                  int* __restrict__ binfill, int* __restrict__ pairs) {
    __shared__ int hist[NBINS];
    __shared__ int base[NBINS];
    int t = threadIdx.x;
    for (int i = t; i < NBINS; i += 1024) hist[i] = 0;
    __syncthreads();
    int e0 = blockIdx.x * EPB;
    int mybin[8], myrank[8], mypack[8];
#pragma unroll
    for (int j = 0; j < 8; ++j) {
        int e = e0 + j * 1024 + t;
        if (e < N_EDGES) {
            int d = dst[e];
            int bin = d >> 6;
            mybin[j] = bin;
            mypack[j] = (src[e] << 6) | (d & 63);
            myrank[j] = atomicAdd(&hist[bin], 1);
        } else {
            mybin[j] = -1;
        }
    }
    __syncthreads();
    for (int i = t; i < NBINS; i += 1024) base[i] = atomicAdd(&binfill[i], hist[i]);
    __syncthreads();
#pragma unroll
    for (int j = 0; j < 8; ++j) {
        if (mybin[j] >= 0) {
            int bin = mybin[j];
            int pos = base[bin] + myrank[j];
            if (pos < CAP) pairs[bin * CAP + pos] = mypack[j];
        }
    }
}

// ---------------- bin solve ----------------

__global__ __launch_bounds__(256) void k_binsolve(const int* __restrict__ pairs, const int* __restrict__ binfill,
                                                  u16* __restrict__ srt, int* __restrict__ rowbeg,
                                                  int* __restrict__ degA, int* __restrict__ order) {
    __shared__ int lcnt[64];
    __shared__ int lptr[64];
    __shared__ int lcur[64];
    __shared__ int h8[8];
    __shared__ int bb[8];
    int bin = blockIdx.x;
    int t = threadIdx.x;
    int p0 = bin * CAP;
    int cnt = min(binfill[bin], CAP);
    if (t < 64) lcnt[t] = 0;
    if (t < 8) h8[t] = 0;
    __syncthreads();
    for (int i = t; i < cnt; i += 256) atomicAdd(&lcnt[pairs[p0 + i] & 63], 1);
    __syncthreads();
    if (t < 64) {
        int d = lcnt[t];
        int v = d;
#pragma unroll
        for (int off = 1; off < 64; off <<= 1) {
            int u = __shfl_up(v, off);
            if (t >= off) v += u;
        }
        lptr[t] = v - d;
        lcur[t] = v - d;
    }
    __syncthreads();
    for (int i = t; i < cnt; i += 256) {
        int p = pairs[p0 + i];
        int slot = atomicAdd(&lcur[p & 63], 1);
        srt[p0 + slot] = (u16)(p >> 6);
    }
    int node = bin * 64 + t;
    bool act = (t < 64) && (node < N_NODES);
    int b = 0, r8 = 0;
    if (act) {
        rowbeg[node] = p0 + lptr[t];
        degA[node] = lcnt[t];
        b = bucketof(lcnt[t]);
        r8 = atomicAdd(&h8[b], 1);
    }
    __syncthreads();
    if (t == 0) {
        int r = 0;
#pragma unroll
        for (int i = 0; i < 8; ++i) { bb[i] = r; r += h8[i]; }
    }
    __syncthreads();
    if (act) order[bin * 64 + bb[b] + r8] = node;
}

// ---------------- FUSED layer: fp8 gather (bin of 64 nodes -> LDS f16) + dual MFMA GEMM ----------------
// Gather: 16 groups x 16 lanes; each lane 8 fp8 = 8 B; group covers 128 B row = 2 cache lines.
// Self operand: layer 1 from f32 x (cast f16 on the fly), layer 2 from f16 hh.
// Epilogue: C (f32, optional), Cb16 (f16, optional), Cb8 (fp8, optional).

__global__ __launch_bounds__(256) void k_fused(const u8* __restrict__ X8, const float* __restrict__ Xf,
                                               const f16* __restrict__ Xh16, const u16* __restrict__ srt,
                                               const int* __restrict__ rowbeg, const int* __restrict__ degA,
                                               const int* __restrict__ order, const f16* __restrict__ Wf,
                                               const float* __restrict__ bias,
                                               float* __restrict__ C, f16* __restrict__ Cb16,
                                               u8* __restrict__ Cb8) {
    __shared__ f16 agg[64][136];
    int bin = blockIdx.x;
    int n0 = bin << 6;
    int t = threadIdx.x;
    int g = t >> 4, l16 = t & 15;
    int nvalid = N_NODES - n0; if (nvalid > 64) nvalid = 64;
    const u8* __restrict__ base = X8 + l16 * 8;

#pragma unroll
    for (int p = 0; p < 4; ++p) {
        int rank = p * 16 + g;
        if (rank < nvalid) {
            int node = order[n0 + rank];
            int m = node - n0;
            int beg = rowbeg[node];
            int d = degA[node];
            int end = beg + d;
            f32x2 A0[4], A1[4], A2[4], A3[4];
#pragma unroll
            for (int j = 0; j < 4; ++j) {
                A0[j] = (f32x2){0.f, 0.f}; A1[j] = (f32x2){0.f, 0.f};
                A2[j] = (f32x2){0.f, 0.f}; A3[j] = (f32x2){0.f, 0.f};
            }
            int e = beg;
#define GACC(Ar, w) { Ar[0] += __builtin_amdgcn_cvt_pk_f32_fp8((w).x, false); \
                      Ar[1] += __builtin_amdgcn_cvt_pk_f32_fp8((w).x, true);  \
                      Ar[2] += __builtin_amdgcn_cvt_pk_f32_fp8((w).y, false); \
                      Ar[3] += __builtin_amdgcn_cvt_pk_f32_fp8((w).y, true); }
            for (; e + 4 <= end; e += 4) {
                int s0 = __builtin_nontemporal_load(srt + e);
                int s1 = __builtin_nontemporal_load(srt + e + 1);
                int s2 = __builtin_nontemporal_load(srt + e + 2);
                int s3 = __builtin_nontemporal_load(srt + e + 3);
                uint2 w0 = *(const uint2*)(base + (size_t)s0 * DIM);
                uint2 w1 = *(const uint2*)(base + (size_t)s1 * DIM);
                uint2 w2 = *(const uint2*)(base + (size_t)s2 * DIM);
                uint2 w3 = *(const uint2*)(base + (size_t)s3 * DIM);
                GACC(A0, w0); GACC(A1, w1); GACC(A2, w2); GACC(A3, w3);
            }
            if (e < end)     { uint2 w = *(const uint2*)(base + (size_t)__builtin_nontemporal_load(srt + e) * DIM); GACC(A0, w); }
            if (e + 1 < end) { uint2 w = *(const uint2*)(base + (size_t)__builtin_nontemporal_load(srt + e + 1) * DIM); GACC(A1, w); }
            if (e + 2 < end) { uint2 w = *(const uint2*)(base + (size_t)__builtin_nontemporal_load(srt + e + 2) * DIM); GACC(A2, w); }
#undef GACC
            float inv = 1.0f / fmaxf((float)d, 1.0f);
            f16x8 r;
#pragma unroll
            for (int j = 0; j < 4; ++j) {
                f32x2 s = (A0[j] + A1[j]) + (A2[j] + A3[j]);
                r[j * 2]     = (f16)(s.x * inv);
                r[j * 2 + 1] = (f16)(s.y * inv);
            }
            *(f16x8*)&agg[m][l16 * 8] = r;
        }
    }
    __syncthreads();

    int wave = t >> 6, lane = t & 63;
    int r = lane & 15, gg = lane >> 4;
    int rowloc = wave * 16 + r;
    size_t grow = (size_t)n0 + rowloc;
    size_t growc = (grow < N_NODES) ? grow : (N_NODES - 1);

    f32x4 acc[8];
#pragma unroll
    for (int nt = 0; nt < 8; ++nt) acc[nt] = (f32x4){0.f, 0.f, 0.f, 0.f};

#pragma unroll
    for (int kk = 0; kk < 8; ++kk) {
        f16x8 a;
        if (kk < 4) {
            f16x4 q0 = *(const f16x4*)&agg[rowloc][kk * 32 + gg * 4];
            f16x4 q1 = *(const f16x4*)&agg[rowloc][kk * 32 + gg * 4 + 16];
            a = __builtin_shufflevector(q0, q1, 0, 1, 2, 3, 4, 5, 6, 7);
        } else if (Xf) {
            const float* ar = Xf + growc * DIM + (kk - 4) * 32 + gg * 4;
            float4 u0 = *(const float4*)(ar);
            float4 u1 = *(const float4*)(ar + 16);
            a[0]=(f16)u0.x; a[1]=(f16)u0.y; a[2]=(f16)u0.z; a[3]=(f16)u0.w;
            a[4]=(f16)u1.x; a[5]=(f16)u1.y; a[6]=(f16)u1.z; a[7]=(f16)u1.w;
        } else {
            const f16* ar = Xh16 + growc * DIM + (kk - 4) * 32 + gg * 4;
            f16x4 q0 = *(const f16x4*)(ar);
            f16x4 q1 = *(const f16x4*)(ar + 16);
            a = __builtin_shufflevector(q0, q1, 0, 1, 2, 3, 4, 5, 6, 7);
        }
#pragma unroll
        for (int nt = 0; nt < 8; ++nt) {
            f16x8 b = *(const f16x8*)(Wf + ((size_t)((nt * 8 + kk) * 64 + lane)) * 8);
            acc[nt] = __builtin_amdgcn_mfma_f32_16x16x32_f16(a, b, acc[nt], 0, 0, 0);
        }
    }
    size_t rbase = (size_t)n0 + wave * 16 + gg * 4;
#pragma unroll
    for (int nt = 0; nt < 8; ++nt) {
        int colc = nt * 16 + r;
        float bv = bias[colc];
#pragma unroll
        for (int q = 0; q < 4; ++q) {
            size_t node = rbase + q;
            if (node < N_NODES) {
                float v = fmaxf(acc[nt][q] + bv, 0.f);
                if (C)    C[node * DIM + colc] = v;
                if (Cb16) Cb16[node * DIM + colc] = (f16)v;
                if (Cb8) {
                    int pk = __builtin_amdgcn_cvt_pk_fp8_f32(v, v, 0, false);
                    Cb8[node * DIM + colc] = (u8)(pk & 0xff);
                }
            }
        }
    }
}

// ---------------- launch ----------------

extern "C" void kernel_launch(void* const* d_in, const int* in_sizes, int n_in,
                              void* d_out, int out_size, void* d_ws, size_t ws_size,
                              hipStream_t stream) {
    const float* x   = (const float*)d_in[0];
    const int*   ei  = (const int*)d_in[1];
    const float* W1l = (const float*)d_in[2];
    const float* b1  = (const float*)d_in[3];
    const float* W1r = (const float*)d_in[4];
    const float* W2l = (const float*)d_in[5];
    const float* b2  = (const float*)d_in[6];
    const float* W2r = (const float*)d_in[7];
    float* out = (float*)d_out;

    const int* src = ei;
    const int* dst = ei + N_EDGES;

    char* ws = (char*)d_ws;
    int*  binfill = (int*)(ws + 0);              // 3,128 B (zeroed by prep block 3157)
    int*  degA    = (int*)(ws + 3200);           // 200,000 B
    int*  rowbeg  = (int*)(ws + 203264);         // 200,000 B
    int*  order   = (int*)(ws + 403264);         // 200,000 B
    u16*  srt     = (u16*)(ws + 603264);         // 3,203,072 B -> ends 3,806,336
    u8*   x8      = (u8*)(ws + 3806336);         // 6.4 MB fp8 x -> ends 10,206,336
    f16*  hh      = (f16*)(ws + 10206336);       // 12.8 MB f16 h -> ends 23,006,336
    int*  pairs   = (int*)(ws + 23006336);       // 6,406,144 B -> ends 29,412,480
    u8*   hh8     = (u8*)(ws + 23006336);        // 6.4 MB fp8 h (overlaps pairs; pairs dead after binsolve)
    f16*  Wf1     = (f16*)(ws + 29412480);       // 64 KB frag-order
    f16*  Wf2     = Wf1 + 32768;                 // 64 KB -> ends ~29.54 MB

    dim3 blk(256);
    k_prep<<<dim3(3158), blk, 0, stream>>>(x, x8, W1l, W1r, W2l, W2r, Wf1, Wf2, binfill);
    k_binscat<<<dim3(NSCAT), dim3(1024), 0, stream>>>(src, dst, binfill, pairs);
    k_binsolve<<<dim3(NBINS), blk, 0, stream>>>(pairs, binfill, srt, rowbeg, degA, order);

    // layer 1: h = relu(agg8(x) @ W1l^T + b1 + x @ W1r^T)   -> hh (f16) + hh8 (fp8)
    k_fused<<<dim3(NBINS), blk, 0, stream>>>(x8, x, (const f16*)nullptr, srt, rowbeg, degA, order,
                                             Wf1, b1, (float*)nullptr, hh, hh8);

    // layer 2: out = relu(agg8(h) @ W2l^T + b2 + h @ W2r^T) -> out (f32)
    k_fused<<<dim3(NBINS), blk, 0, stream>>>(hh8, (const float*)nullptr, hh, srt, rowbeg, degA, order,
                                             Wf2, b2, out, (f16*)nullptr, (u8*)nullptr);
}